// Round 9
// baseline (236.617 us; speedup 1.0000x reference)
//
#include <hip/hip_runtime.h>
#include <stdint.h>

// ---------------------------------------------------------------------------
// RoIHead: out = crop_and_resize(feature, rois) @ (W_fc @ [W_loc|W_score])
//                + (b_fc @ [W_loc|W_score] + [b_loc|b_score])
// 413 GF -> 32 GF. Floor: 411 MB W_fc + 100 MB pool = ~81 us HBM.
// R9: PURE-gll16 gemm1. R2-R8 all staged A through registers; LLVM's waitcnt
// pass can't track counters across inline-asm, so it guards every reg-use
// with a conservative vmcnt(0) -> full drain per phase (matches measured
// 4163 cyc/phase). global_load_lds has NO register destination -> nothing to
// guard -> counted vmcnt(8) is the only gate. A staged as fp32 (source-
// swizzled per-lane so linear LDS write = swizzled layout; cvt after read).
// ---------------------------------------------------------------------------

typedef float          f32x4 __attribute__((ext_vector_type(4)));
typedef __bf16         bfx8  __attribute__((ext_vector_type(8)));
typedef __bf16         bfx4  __attribute__((ext_vector_type(4)));
typedef __bf16         bfx2  __attribute__((ext_vector_type(2)));

#define KBIG 25088   // 7*7*512
#define NMID 4096    // FC_OUT
#define NROIS 2000
#define G1BLOCKS 784 // 392 m-tiles x 2 k-splits
#define SPLITS 28    // gemm2 K-splits (392 BK steps = 28*14)

__device__ __forceinline__ void gll16(const void* g, void* l) {
  __builtin_amdgcn_global_load_lds(
      (const __attribute__((address_space(1))) void*)(uintptr_t)(g),
      (__attribute__((address_space(3))) void*)(uintptr_t)(l), 16, 0, 0);
}

// ---------------------------------------------------------------------------
// prep: blocks 0..2047 build WcatT[128][4096] bf16 (zero-padded cols>=105);
//       blocks 2048..2175 compute bc[c] = b_fc . Wcat[:,c] + bias[c].
// ---------------------------------------------------------------------------
__global__ __launch_bounds__(256) void k_prep(const float* __restrict__ Wl,
                                              const float* __restrict__ Ws,
                                              const float* __restrict__ bfc,
                                              const float* __restrict__ bl,
                                              const float* __restrict__ bs,
                                              unsigned short* __restrict__ WcatT,
                                              float* __restrict__ bc) {
  if (blockIdx.x < 2048) {
    int idx = blockIdx.x * 256 + threadIdx.x;
    int c = idx >> 12, k = idx & 4095;
    float v = 0.0f;
    if (c < 84)       v = Wl[k * 84 + c];
    else if (c < 105) v = Ws[k * 21 + (c - 84)];
    ((__bf16*)WcatT)[idx] = (__bf16)v;
  } else {
    int c = blockIdx.x - 2048;   // 0..127
    int t = threadIdx.x;
    __shared__ float red[256];
    float p = 0.0f;
    if (c < 105) {
      for (int k = t; k < 4096; k += 256) {
        float w = (c < 84) ? Wl[k * 84 + c] : Ws[k * 21 + (c - 84)];
        p += bfc[k] * w;
      }
    }
    red[t] = p;
    __syncthreads();
    for (int s = 128; s > 0; s >>= 1) {
      if (t < s) red[t] += red[t + s];
      __syncthreads();
    }
    if (t == 0) {
      float bias = (c < 84) ? bl[c] : (c < 105 ? bs[c - 84] : 0.0f);
      bc[c] = (c < 105) ? (red[0] + bias) : 0.0f;
    }
  }
}

// ---------------------------------------------------------------------------
// Fused: blocks [0,784) = GEMM1 (mt = bx>>1, ksplit = bx&1), [784,2784) = pool.
// GEMM1: Pg1[sp][n][m] f32 partial of (W_fc @ WcatT^T)^T. BM=64 BN=128 BK=64.
//   A: fp32 via gll16 into sA[2][64][256B]. Source-swizzle: lane fetches
//      logical 16B-chunk (l&15)^(r&15) -> linear HW write = XOR-swizzled
//      layout; frag reads 2-way-conflict-free; cvt fp32->bf16 after read.
//   B: bf16 via gll16 into sB[2][128][128B] (jlog pattern, as R2..R8).
//   Phase: stageA(c+1)+stageB(c+1) [one 8-op group], vmcnt(8) [retires the
//   previous group exactly; order-robust], s_barrier, compute(c), s_barrier.
//   NO reg-dest global loads in the loop -> no compiler waitcnt drains.
// ---------------------------------------------------------------------------
__global__ __launch_bounds__(256, 2) void k_pool_gemm1(
    const float* __restrict__ F, const float* __restrict__ rois,
    const int* __restrict__ ihp, const int* __restrict__ iwp,
    unsigned short* __restrict__ A,
    const float* __restrict__ Wfc, const unsigned short* __restrict__ WcatT,
    float* __restrict__ Pg1) {
  const int t = threadIdx.x;
  __shared__ __align__(16) char sA[32768];   // [2][64 rows][256 B] fp32
  __shared__ __align__(16) char sB[32768];   // [2][128 rows][128 B] bf16
  if (blockIdx.x < G1BLOCKS) {
    // ---------------- GEMM1 ----------------
    const int lane = t & 63, wid = t >> 6;
    const int wm = wid >> 1, wn = wid & 1;
    const int l15 = lane & 15, l4 = lane >> 4;
    const int mt = blockIdx.x >> 1, sp = blockIdx.x & 1;
    const int m0 = mt * 64;
    const int kbase = sp * 2048;
    const int rot = mt & 31;
    const int jlog = (t & 7) ^ ((t >> 3) & 7);
    f32x4 acc[2][4] = {};

    const float* abase = Wfc + (size_t)m0 * NMID + kbase;
    // stageA: thread op q -> wave op o=wid*4+q covers LDS rows o*4..o*4+3.
    // lane: row r = o*4 + (l>>4); fetches logical chunk (l&15)^(r&15).
    const int arow_lo = lane >> 4;            // row within op's 4-row window
    const int aswz = lane & 15;               // l&15

    auto rc = [&](int c) { return (c + rot) & 31; };

    auto stageA = [&](int c, int off) {
      const int k0 = rc(c) * 64;
#pragma unroll
      for (int q = 0; q < 4; ++q) {
        const int o = wid * 4 + q;
        const int r = o * 4 + arow_lo;
        const int clog = aswz ^ (r & 15);
        gll16(abase + (size_t)r * NMID + k0 + clog * 4, sA + off + o * 1024);
      }
    };
    auto stageB = [&](int c, int off) {
      const int k0 = rc(c) * 64;
#pragma unroll
      for (int q = 0; q < 4; ++q)
        gll16(WcatT + (size_t)(q * 32 + (t >> 3)) * NMID + kbase + k0 + jlog * 8,
              sB + off + q * 4096 + wid * 1024);
    };
    auto compute = [&](int aoff, int boff) {
#pragma unroll
      for (int kk = 0; kk < 2; ++kk) {
        bfx8 af[2];
#pragma unroll
        for (int mi = 0; mi < 2; ++mi) {
          const int R = wm * 32 + mi * 16 + l15;
          const int cb = kk * 8 + l4 * 2;
          f32x4 a0 = *(const f32x4*)(sA + aoff + R * 256 + (((cb + 0) ^ (R & 15)) << 4));
          f32x4 a1 = *(const f32x4*)(sA + aoff + R * 256 + (((cb + 1) ^ (R & 15)) << 4));
          bfx8 tb;
#pragma unroll
          for (int j = 0; j < 4; ++j) {
            tb[j] = (__bf16)a0[j];
            tb[j + 4] = (__bf16)a1[j];
          }
          af[mi] = tb;
        }
        bfx8 bfr[4];
#pragma unroll
        for (int ni = 0; ni < 4; ++ni) {
          const int row = wn * 64 + ni * 16 + l15;
          bfr[ni] = *(const bfx8*)(sB + boff + row * 128 + ((((kk << 2) + l4) ^ (row & 7)) << 4));
        }
#pragma unroll
        for (int mi = 0; mi < 2; ++mi)
#pragma unroll
          for (int ni = 0; ni < 4; ++ni)
            acc[mi][ni] = __builtin_amdgcn_mfma_f32_16x16x32_bf16(af[mi], bfr[ni], acc[mi][ni], 0, 0, 0);
      }
    };

    // prologue: group(0) -> bufs 0
    stageA(0, 0);
    stageB(0, 0);
    for (int cc = 0; cc < 16; ++cc) {
      const int c0 = cc * 2;
      // even: stage c0+1 -> buf1; compute c0 (buf0)
      stageA(c0 + 1, 16384);
      stageB(c0 + 1, 16384);
      asm volatile("s_waitcnt vmcnt(8)" ::: "memory");
      __builtin_amdgcn_s_barrier();
      __builtin_amdgcn_sched_barrier(0);
      compute(0, 0);
      __builtin_amdgcn_s_barrier();
      // odd: stage c0+2 -> buf0 (clamped dup at tail, never computed); compute c0+1
      const int cn = (c0 + 2 < 32) ? c0 + 2 : 31;
      stageA(cn, 0);
      stageB(cn, 0);
      asm volatile("s_waitcnt vmcnt(8)" ::: "memory");
      __builtin_amdgcn_s_barrier();
      __builtin_amdgcn_sched_barrier(0);
      compute(16384, 16384);
      __builtin_amdgcn_s_barrier();
    }
    asm volatile("s_waitcnt vmcnt(0)" ::: "memory");
    // epilogue: D col(lane&15)=n, row((lane>>4)*4+i)=m -> 16B f32 stores
#pragma unroll
    for (int mi = 0; mi < 2; ++mi)
#pragma unroll
      for (int ni = 0; ni < 4; ++ni) {
        const int n = wn * 64 + ni * 16 + l15;
        float* dst = Pg1 + ((size_t)sp * 128 + n) * KBIG + m0 + wm * 32 + mi * 16 + l4 * 4;
        *(f32x4*)dst = acc[mi][ni];
      }
  } else {
    // ---------------- pool (next-cell prefetch) ----------------
    const int r = blockIdx.x - G1BLOCKS;
    const float ih = (float)ihp[0], iw = (float)iwp[0];
    const float y1 = rois[r * 4 + 0] / ih;
    const float x1 = rois[r * 4 + 1] / iw;
    const float y2 = rois[r * 4 + 2] / ih;
    const float x2 = rois[r * 4 + 3] / iw;
    const float sy = (y2 - y1) * 49.0f / 6.0f;
    const float sx = (x2 - x1) * 49.0f / 6.0f;
    const int ch = t * 2;
    __bf16* __restrict__ Arow = (__bf16*)(A + (size_t)r * KBIG);

    auto cellcoords = [&](int cell, int& o00, int& o01, int& o10, int& o11,
                          float& yl, float& xl, bool& valid) {
      const int iy = cell / 7, ix = cell - iy * 7;
      const float in_y = y1 * 49.0f + (float)iy * sy;
      const float in_x = x1 * 49.0f + (float)ix * sx;
      const float y0f = floorf(in_y), x0f = floorf(in_x);
      yl = in_y - y0f; xl = in_x - x0f;
      const int y0  = (int)fminf(fmaxf(y0f, 0.0f), 49.0f);
      const int y1i = (int)fminf(fmaxf(y0f + 1.0f, 0.0f), 49.0f);
      const int x0  = (int)fminf(fmaxf(x0f, 0.0f), 49.0f);
      const int x1i = (int)fminf(fmaxf(x0f + 1.0f, 0.0f), 49.0f);
      valid = (in_y >= 0.0f) && (in_y <= 49.0f) && (in_x >= 0.0f) && (in_x <= 49.0f);
      o00 = (y0 * 50 + x0) * 512;  o01 = (y0 * 50 + x1i) * 512;
      o10 = (y1i * 50 + x0) * 512; o11 = (y1i * 50 + x1i) * 512;
    };

    int o00, o01, o10, o11; float yl, xl; bool valid;
    cellcoords(0, o00, o01, o10, o11, yl, xl, valid);
    float2 f00 = *(const float2*)&F[o00 + ch];
    float2 f01 = *(const float2*)&F[o01 + ch];
    float2 f10 = *(const float2*)&F[o10 + ch];
    float2 f11 = *(const float2*)&F[o11 + ch];

    for (int cell = 0; cell < 49; ++cell) {
      const float2 g00 = f00, g01 = f01, g10 = f10, g11 = f11;
      const float pyl = yl, pxl = xl;
      const bool pv = valid;
      if (cell < 48) {
        cellcoords(cell + 1, o00, o01, o10, o11, yl, xl, valid);
        f00 = *(const float2*)&F[o00 + ch];
        f01 = *(const float2*)&F[o01 + ch];
        f10 = *(const float2*)&F[o10 + ch];
        f11 = *(const float2*)&F[o11 + ch];
      }
      float oA = 0.0f, oB = 0.0f;
      if (pv) {
        float t0 = g00.x * (1.0f - pxl) + g01.x * pxl;
        float t1 = g00.y * (1.0f - pxl) + g01.y * pxl;
        float b0 = g10.x * (1.0f - pxl) + g11.x * pxl;
        float b1 = g10.y * (1.0f - pxl) + g11.y * pxl;
        oA = t0 * (1.0f - pyl) + b0 * pyl;
        oB = t1 * (1.0f - pyl) + b1 * pyl;
      }
      bfx2 v; v[0] = (__bf16)oA; v[1] = (__bf16)oB;
      *(bfx2*)(Arow + cell * 512 + ch) = v;
    }
  }
}

// ---------------------------------------------------------------------------
// addcvt: WcT[n][m] bf16 = Pg1[0][n][m] + Pg1[1][n][m]
// ---------------------------------------------------------------------------
__global__ __launch_bounds__(256) void k_addcvt(const float* __restrict__ Pg1,
                                                unsigned short* __restrict__ WcT) {
  const size_t i = ((size_t)blockIdx.x * 256 + threadIdx.x) * 8;  // < 128*25088
  f32x4 a0 = *(const f32x4*)(Pg1 + i);
  f32x4 a1 = *(const f32x4*)(Pg1 + i + 4);
  f32x4 b0 = *(const f32x4*)(Pg1 + 3211264 + i);
  f32x4 b1 = *(const f32x4*)(Pg1 + 3211264 + i + 4);
  bfx8 o;
#pragma unroll
  for (int j = 0; j < 4; ++j) {
    o[j]     = (__bf16)(a0[j] + b0[j]);
    o[j + 4] = (__bf16)(a1[j] + b1[j]);
  }
  *(bfx8*)(WcT + i) = o;
}

// ---------------------------------------------------------------------------
// GEMM2: P[mt*28+sp][64][128] f32 = pool_tile(mt) @ WcT_slice(sp).
// Counted-vmcnt double buffer: stage(c+1); vmcnt(6); barrier; compute(c);
// barrier. One 6-op staging group per region -> count is order-robust.
// ---------------------------------------------------------------------------
__global__ __launch_bounds__(256) void k_gemm2(const unsigned short* __restrict__ Ap,
                                               const unsigned short* __restrict__ WcT,
                                               float* __restrict__ P) {
  __shared__ __align__(16) char S[49152];
  const int t = threadIdx.x;
  const int lane = t & 63, wid = t >> 6;
  const int wm = wid >> 1, wn = wid & 1;
  const int l15 = lane & 15, l4 = lane >> 4;
  const int mt = blockIdx.x, sp = blockIdx.y;
  const int kbase = sp * 896;     // 14 BK-steps of 64
  const int jlog = (t & 7) ^ ((t >> 3) & 7);
  f32x4 acc[2][4] = {};

  int ar0 = mt * 64 + (t >> 3);
  int ar1 = ar0 + 32;
  if (ar0 > NROIS - 1) ar0 = NROIS - 1;
  if (ar1 > NROIS - 1) ar1 = NROIS - 1;
  const unsigned short* asrc0 = Ap + (size_t)ar0 * KBIG + jlog * 8;
  const unsigned short* asrc1 = Ap + (size_t)ar1 * KBIG + jlog * 8;

  auto stage2 = [&](int c, int off) {
    const int k0 = kbase + c * 64;
    gll16(asrc0 + k0, S + off + wid * 1024);
    gll16(asrc1 + k0, S + off + 4096 + wid * 1024);
#pragma unroll
    for (int q = 0; q < 4; ++q)
      gll16(WcT + (size_t)(q * 32 + (t >> 3)) * KBIG + k0 + jlog * 8,
            S + off + 8192 + q * 4096 + wid * 1024);
  };
  auto compute2 = [&](int off) {
#pragma unroll
    for (int kh = 0; kh < 2; ++kh) {
      bfx8 af[2], bfr[4];
#pragma unroll
      for (int mi = 0; mi < 2; ++mi) {
        const int row = wm * 32 + mi * 16 + l15;
        af[mi] = *(const bfx8*)(S + off + row * 128 + ((((kh << 2) + l4) ^ (row & 7)) << 4));
      }
#pragma unroll
      for (int ni = 0; ni < 4; ++ni) {
        const int row = wn * 64 + ni * 16 + l15;
        bfr[ni] = *(const bfx8*)(S + off + 8192 + row * 128 + ((((kh << 2) + l4) ^ (row & 7)) << 4));
      }
#pragma unroll
      for (int mi = 0; mi < 2; ++mi)
#pragma unroll
        for (int ni = 0; ni < 4; ++ni)
          acc[mi][ni] = __builtin_amdgcn_mfma_f32_16x16x32_bf16(af[mi], bfr[ni], acc[mi][ni], 0, 0, 0);
    }
  };

  stage2(0, 0);
  for (int cc = 0; cc < 7; ++cc) {
    const int c0 = cc * 2;
    stage2(c0 + 1, 24576);
    asm volatile("s_waitcnt vmcnt(6)" ::: "memory");
    __builtin_amdgcn_s_barrier();
    __builtin_amdgcn_sched_barrier(0);
    compute2(0);
    __builtin_amdgcn_s_barrier();
    stage2((c0 + 2 < 14) ? c0 + 2 : 13, 0);
    asm volatile("s_waitcnt vmcnt(6)" ::: "memory");
    __builtin_amdgcn_s_barrier();
    __builtin_amdgcn_sched_barrier(0);
    compute2(24576);
    __builtin_amdgcn_s_barrier();
  }
  asm volatile("s_waitcnt vmcnt(0)" ::: "memory");
  float* out = P + (size_t)(mt * SPLITS + sp) * 8192;
#pragma unroll
  for (int mi = 0; mi < 2; ++mi)
#pragma unroll
    for (int ni = 0; ni < 4; ++ni)
#pragma unroll
      for (int i = 0; i < 4; ++i)
        out[(wm * 32 + mi * 16 + l4 * 4 + i) * 128 + wn * 64 + ni * 16 + l15] = acc[mi][ni][i];
}

// ---------------------------------------------------------------------------
// reduce: sum 28 K-split partials + bias, scatter into the two outputs.
// ---------------------------------------------------------------------------
__global__ __launch_bounds__(128) void k_reduce(const float* __restrict__ P,
                                                const float* __restrict__ bc,
                                                float* __restrict__ out) {
  const int m = blockIdx.x;     // 0..1999
  const int c = threadIdx.x;    // 0..127
  if (c >= 105) return;
  const int mt = m >> 6, r = m & 63;
  float sum = 0.0f;
#pragma unroll
  for (int s = 0; s < SPLITS; ++s)
    sum += P[(size_t)(mt * SPLITS + s) * 8192 + r * 128 + c];
  sum += bc[c];
  if (c < 84) out[m * 84 + c] = sum;
  else        out[168000 + m * 21 + (c - 84)] = sum;
}

// ---------------------------------------------------------------------------
extern "C" void kernel_launch(void* const* d_in, const int* in_sizes, int n_in,
                              void* d_out, int out_size, void* d_ws, size_t ws_size,
                              hipStream_t stream) {
  const float* F    = (const float*)d_in[0];
  const float* rois = (const float*)d_in[1];
  const int*   ih   = (const int*)d_in[2];
  const int*   iw   = (const int*)d_in[3];
  const float* Wfc  = (const float*)d_in[4];
  const float* bfc  = (const float*)d_in[5];
  const float* Wl   = (const float*)d_in[6];
  const float* bl   = (const float*)d_in[7];
  const float* Ws   = (const float*)d_in[8];
  const float* bs   = (const float*)d_in[9];
  (void)in_sizes; (void)n_in; (void)out_size; (void)ws_size;

  char* ws = (char*)d_ws;
  // ws layout (bytes):
  //   pool  bf16 [2000][25088]      @ 0          (100,352,000)
  //   WcatT bf16 [128][4096]        @ 100352000  (1,048,576)
  //   WcT   bf16 [128][25088]       @ 101400576  (6,422,528)
  //   bc    f32  [128]              @ 107823104  (512)
  //   P     f32  [896][64][128]     @ 107823616  (29,360,128)
  //   Pg1   f32  [2][128][25088]    @ 137183744  (25,690,112)  total ~163 MB
  unsigned short* Apool = (unsigned short*)(ws);
  unsigned short* WcatT = (unsigned short*)(ws + 100352000);
  unsigned short* WcT   = (unsigned short*)(ws + 101400576);
  float*          bc    = (float*)(ws + 107823104);
  float*          P     = (float*)(ws + 107823616);
  float*          Pg1   = (float*)(ws + 137183744);
  float*          out   = (float*)d_out;

  k_prep      <<<2176, 256, 0, stream>>>(Wl, Ws, bfc, bl, bs, WcatT, bc);
  k_pool_gemm1<<<G1BLOCKS + NROIS, 256, 0, stream>>>(F, rois, ih, iw, Apool,
                                                     Wfc, WcatT, Pg1);
  k_addcvt    <<<1568, 256, 0, stream>>>(Pg1, WcT);
  k_gemm2     <<<dim3(32, SPLITS), 256, 0, stream>>>(Apool, WcT, P);
  k_reduce    <<<NROIS, 128, 0, stream>>>(P, bc, out);
}